// Round 5
// baseline (285.220 us; speedup 1.0000x reference)
//
#include <hip/hip_runtime.h>
#include <math.h>

#define VOCAB  100000
#define DIM    300
#define BB     4096
#define LL     200
#define HIDDEN 1000
#define OUTC   3
#define KT     19          // ceil(600/32) k-tiles of 32
#define NT     64          // n-tiles of 16, padded 1000 -> 1024
#define MTILES (BB / 16)   // 256 m-tiles of 16 rows

#define QSCALE (6.0f / 127.0f)
#define QINV   (127.0f / 6.0f)

#define W1_BLKS   ((KT * NT * 64 + 255) / 256)     // 304
#define INIT_BLKS ((BB * OUTC + 255) / 256)        // 48
#define CONV_BLKS ((VOCAB * 20 + 255) / 256)       // 7813

// embQ layout: 8 slabs x VOCAB rows x 10 dwords (40 B).  Slab s holds dims
// [40s, 40s+40) of every vocab row (slab 7: dims 280-299 + 20 pad bytes).
// Slab = 4.0 MB -> fits one XCD's L2; gather blocks pin slab to XCD via %8.
#define SLABDW (VOCAB * 10)

typedef __attribute__((ext_vector_type(8))) short  short8;
typedef __attribute__((ext_vector_type(4))) float  floatx4;
typedef __attribute__((ext_vector_type(2))) unsigned short ushort2v;

__device__ inline ushort f2bf(float f) {            // RNE float -> bf16 bits
    union { float f; unsigned u; } v; v.f = f;
    unsigned u = v.u;
    u += 0x7fffu + ((u >> 16) & 1u);
    return (ushort)(u >> 16);
}
__device__ inline float4 f4max(float4 a, float4 b) {
    return make_float4(fmaxf(a.x, b.x), fmaxf(a.y, b.y), fmaxf(a.z, b.z), fmaxf(a.w, b.w));
}
__device__ inline float4 f4add(float4 a, float4 b) {
    return make_float4(a.x + b.x, a.y + b.y, a.z + b.z, a.w + b.w);
}
__device__ inline unsigned pkmax16(unsigned a, unsigned b) {  // packed u16 max
    union { unsigned u; ushort2v v; } x, y, r;
    x.u = a; y.u = b;
    r.v = __builtin_elementwise_max(x.v, y.v);
    return r.u;
}

// slot (in ushorts) of element k, row-in-tile ml, in blocked A [kt][64][8]
__device__ inline int a_slot(int k, int ml) {
    const int kt = k >> 5, kk = k & 31;
    return ((kt << 6) + ml + ((kk >> 3) << 4)) * 8 + (kk & 7);
}

__device__ inline unsigned q4(float a, float b, float c, float d) {
    int q0 = min(max(__float2int_rn(a * QINV) + 128, 0), 255);
    int q1 = min(max(__float2int_rn(b * QINV) + 128, 0), 255);
    int q2 = min(max(__float2int_rn(c * QINV) + 128, 0), 255);
    int q3 = min(max(__float2int_rn(d * QINV) + 128, 0), 255);
    return (unsigned)q0 | ((unsigned)q1 << 8) | ((unsigned)q2 << 16) | ((unsigned)q3 << 24);
}

// ---------------------------------------------------------------------------
// prep_all: [0,W1_BLKS) pack W1 -> bf16 B-frag; [..+INIT_BLKS) out=b2;
// [..+CONV_BLKS) quantize emb -> slab-major uint8 table (only if doConv).
// ---------------------------------------------------------------------------
__global__ __launch_bounds__(256) void prep_all(
    const float* __restrict__ emb, unsigned* __restrict__ embQ,
    const float* __restrict__ W1,  ushort* __restrict__ w1p,
    const float* __restrict__ b2,  float* __restrict__ out)
{
    const int bid = blockIdx.x;
    const int tid = threadIdx.x;
    if (bid < W1_BLKS) {
        const int g = bid * 256 + tid;                 // (kt*NT + nt)*64 + lane
        if (g >= KT * NT * 64) return;
        const int lane = g & 63;
        const int nt   = (g >> 6) & (NT - 1);
        const int kt   = g >> 12;
        const int n    = nt * 16 + (lane & 15);
        const int kb   = kt * 32 + ((lane >> 4) << 3);
        short8 v;
        #pragma unroll
        for (int j = 0; j < 8; ++j) {
            const int k = kb + j;
            const float f = (k < 600 && n < HIDDEN) ? W1[k * HIDDEN + n] : 0.f;
            v[j] = (short)f2bf(f);
        }
        ((short8*)w1p)[g] = v;
    } else if (bid < W1_BLKS + INIT_BLKS) {
        const int g = (bid - W1_BLKS) * 256 + tid;
        if (g < BB * OUTC) out[g] = b2[g % OUTC];
    } else {
        const int g = (bid - W1_BLKS - INIT_BLKS) * 256 + tid;   // row*20 + c
        if (g >= VOCAB * 20) return;
        const int row = g / 20;
        const int c   = g - row * 20;
        const float4* rp = (const float4*)(emb + (size_t)row * DIM);
        #pragma unroll
        for (int v = 0; v < 4; ++v) {
            const int fi = 4 * c + v;            // float4 idx == dword idx [0,80)
            float4 f = (fi < 75) ? rp[fi] : make_float4(0.f, 0.f, 0.f, 0.f);
            const unsigned o  = q4(f.x, f.y, f.z, f.w);
            const int      sl = fi / 10;          // slab
            const int      dw = fi - sl * 10;     // dword within slab row
            embQ[(size_t)sl * SLABDW + row * 10 + dw] = o;
        }
    }
}

// ---------------------------------------------------------------------------
// XCD-sliced int8 gather + pool.  Block = (row, slab): blockIdx = row*8 + s,
// so s == blockIdx % 8 pins slab s to XCD s (round-robin dispatch) -> each
// XCD's random gathers stay inside its 4 MB L2-resident slab.
// Each block owns 40 dims of one row outright (full 200-token sum/max).
// 2 waves split tokens (100 each); lane = token-slot(12) x dword-pair(5):
// 8 B loads, SWAR packed-u16 sums (exact, <= 200*255 < 2^16) and maxes.
// Token-slot fold 12->1 in 3 stages (A: +tg+4,+tg+8 with pre-captured
// shfls; B: +tg+2; C: +tg+1) -- each of the 12 slots counted exactly once
// (round-4's {6,3,2,1} fold double-counted; fixed).
// ---------------------------------------------------------------------------
__global__ __launch_bounds__(128, 8) void gather_pool_i8(
    const unsigned* __restrict__ embQ,
    const int*      __restrict__ x,
    const int*      __restrict__ lengths,
    ushort*         __restrict__ repA)
{
    __shared__ int      xS[LL];
    __shared__ unsigned pX[5][8];      // wave-1 partials (lanes 0..4)

    const int tid  = threadIdx.x;
    const int lane = tid & 63;
    const int wave = tid >> 6;         // 0,1
    const int row  = blockIdx.x >> 3;
    const int s    = blockIdx.x & 7;   // slab -> XCD

    for (int i = tid; i < LL; i += 128) xS[i] = x[row * LL + i];
    const int len = lengths[row];      // >= 1
    __syncthreads();

    const int  slot = lane % 5;        // dword-pair within 40 B slab row
    const int  tg   = lane / 5;        // token-slot 0..11 (12 on lanes 60-63)
    const bool act  = (lane < 60);

    const int t0   = wave * 100;
    const int vmax = min(max(len - t0, 0), 100);
    const int pm_all = vmax / 12;        // p <  pm_all : all 12 tokens in max
    const int pm_any = (vmax + 11) / 12; // p >= pm_any : sum-only

    const unsigned* sb = embQ + (size_t)s * SLABDW + 2 * slot;

    unsigned sL[2] = {0u, 0u}, sH[2] = {0u, 0u};
    unsigned mL[2] = {0u, 0u}, mH[2] = {0u, 0u};
    // max init 0 safe: codes >= 0 and every row has >= 1 valid token.

    int p = 0;
    for (; p < pm_all; ++p) {          // full-max iterations (t <= 95 < 100)
        const int t   = 12 * p + tg;
        const int idx = xS[t0 + t];
        uint2 v = make_uint2(0u, 0u);
        if (act) v = *(const uint2*)(sb + (size_t)idx * 10);
        const unsigned* ww = (const unsigned*)&v;
        #pragma unroll
        for (int w = 0; w < 2; ++w) {
            const unsigned u  = ww[w];
            const unsigned lo = u & 0x00FF00FFu;
            const unsigned hi = (u >> 8) & 0x00FF00FFu;
            sL[w] += lo;  sH[w] += hi;
            mL[w] = pkmax16(mL[w], lo);
            mH[w] = pkmax16(mH[w], hi);
        }
    }
    for (; p < pm_any; ++p) {          // <=1 mixed iteration (per-lane mask)
        const int  t  = 12 * p + tg;
        const bool on = act && (t < 100);
        const int idx = xS[t0 + (on ? t : 0)];
        uint2 v = make_uint2(0u, 0u);
        if (on) v = *(const uint2*)(sb + (size_t)idx * 10);
        const unsigned mk = (t < vmax) ? 0xFFFFFFFFu : 0u;
        const unsigned* ww = (const unsigned*)&v;
        #pragma unroll
        for (int w = 0; w < 2; ++w) {
            const unsigned u  = ww[w];
            const unsigned lo = u & 0x00FF00FFu;
            const unsigned hi = (u >> 8) & 0x00FF00FFu;
            sL[w] += lo;  sH[w] += hi;
            mL[w] = pkmax16(mL[w], lo & mk);
            mH[w] = pkmax16(mH[w], hi & mk);
        }
    }
    for (; p < 9; ++p) {               // sum-only iterations
        const int  t  = 12 * p + tg;
        const bool on = act && (t < 100);
        const int idx = xS[t0 + (on ? t : 0)];
        uint2 v = make_uint2(0u, 0u);
        if (on) v = *(const uint2*)(sb + (size_t)idx * 10);
        const unsigned* ww = (const unsigned*)&v;
        #pragma unroll
        for (int w = 0; w < 2; ++w) {
            const unsigned u = ww[w];
            sL[w] += u & 0x00FF00FFu;
            sH[w] += (u >> 8) & 0x00FF00FFu;
        }
    }

    // ---- fold token-slots 12 -> 1 (result on tg==0, lanes 0..4) ----
    // Stage A: v[tg] += v[tg+4] + v[tg+8]; capture BOTH shfls before adding
    // (a sequential "+= shfl" would read post-add source values).
    {
        const int s1 = slot + 5 * min(tg + 4, 11);
        const int s2 = slot + 5 * min(tg + 8, 11);
        #pragma unroll
        for (int w = 0; w < 2; ++w) {
            const unsigned a1 = (unsigned)__shfl((int)sL[w], s1);
            const unsigned a2 = (unsigned)__shfl((int)sL[w], s2);
            const unsigned b1 = (unsigned)__shfl((int)sH[w], s1);
            const unsigned b2 = (unsigned)__shfl((int)sH[w], s2);
            const unsigned c1v = (unsigned)__shfl((int)mL[w], s1);
            const unsigned c2v = (unsigned)__shfl((int)mL[w], s2);
            const unsigned d1 = (unsigned)__shfl((int)mH[w], s1);
            const unsigned d2 = (unsigned)__shfl((int)mH[w], s2);
            sL[w] += a1 + a2;
            sH[w] += b1 + b2;
            mL[w] = pkmax16(mL[w], pkmax16(c1v, c2v));
            mH[w] = pkmax16(mH[w], pkmax16(d1, d2));
        }
    }
    // Stage B: v[tg] += v[tg+2]  (valid for tg<2; reads stage-A results)
    {
        const int sc = slot + 5 * min(tg + 2, 11);
        #pragma unroll
        for (int w = 0; w < 2; ++w) {
            sL[w] += (unsigned)__shfl((int)sL[w], sc);
            sH[w] += (unsigned)__shfl((int)sH[w], sc);
            mL[w] = pkmax16(mL[w], (unsigned)__shfl((int)mL[w], sc));
            mH[w] = pkmax16(mH[w], (unsigned)__shfl((int)mH[w], sc));
        }
    }
    // Stage C: v[0] += v[1]
    {
        const int sc = slot + 5 * min(tg + 1, 11);
        #pragma unroll
        for (int w = 0; w < 2; ++w) {
            sL[w] += (unsigned)__shfl((int)sL[w], sc);
            sH[w] += (unsigned)__shfl((int)sH[w], sc);
            mL[w] = pkmax16(mL[w], (unsigned)__shfl((int)mL[w], sc));
            mH[w] = pkmax16(mH[w], (unsigned)__shfl((int)mH[w], sc));
        }
    }

    if (wave == 1 && lane < 5) {
        #pragma unroll
        for (int w = 0; w < 2; ++w) {
            pX[lane][w]     = sL[w];
            pX[lane][2 + w] = sH[w];
            pX[lane][4 + w] = mL[w];
            pX[lane][6 + w] = mH[w];
        }
    }
    __syncthreads();
    if (wave == 0 && lane < 5) {
        #pragma unroll
        for (int w = 0; w < 2; ++w) {
            sL[w] += pX[lane][w];
            sH[w] += pX[lane][2 + w];
            mL[w] = pkmax16(mL[w], pX[lane][4 + w]);
            mH[w] = pkmax16(mH[w], pX[lane][6 + w]);
        }

        const float c1 = QSCALE / (float)len;   // mean=(S-128*200)*QSCALE/len
        const int mt = row >> 4;
        const int ml = row & 15;
        ushort* rb = repA + (size_t)mt * (KT * 512);

        #pragma unroll
        for (int w = 0; w < 2; ++w) {
            // dword w of this pair covers dims k0..k0+3
            const int k0 = 40 * s + 8 * slot + 4 * w;
            float S[4], M[4];
            S[0] = (float)(sL[w] & 0xFFFFu);  S[2] = (float)(sL[w] >> 16);
            S[1] = (float)(sH[w] & 0xFFFFu);  S[3] = (float)(sH[w] >> 16);
            M[0] = (float)(mL[w] & 0xFFFFu);  M[2] = (float)(mL[w] >> 16);
            M[1] = (float)(mH[w] & 0xFFFFu);  M[3] = (float)(mH[w] >> 16);
            if (k0 < 300) {                   // real dims (k0 <= 296)
                ushort4 qm = make_ushort4(
                    f2bf((S[0] - 25600.f) * c1), f2bf((S[1] - 25600.f) * c1),
                    f2bf((S[2] - 25600.f) * c1), f2bf((S[3] - 25600.f) * c1));
                *(ushort4*)(rb + a_slot(k0, ml)) = qm;
                ushort4 qx = make_ushort4(
                    f2bf((M[0] - 128.f) * QSCALE), f2bf((M[1] - 128.f) * QSCALE),
                    f2bf((M[2] - 128.f) * QSCALE), f2bf((M[3] - 128.f) * QSCALE));
                *(ushort4*)(rb + a_slot(300 + k0, ml)) = qx;
            } else if (s == 7 && slot == 2 && w == 1) {
                *(ushort4*)(rb + a_slot(600, ml)) = make_ushort4(0, 0, 0, 0);
            } else if (s == 7 && slot == 3 && w == 0) {
                *(ushort4*)(rb + a_slot(604, ml)) = make_ushort4(0, 0, 0, 0);
            }
        }
    }
}

// ---------------------------------------------------------------------------
// fp32 fallback gather (used only if ws too small for embQ).
// ---------------------------------------------------------------------------
__global__ __launch_bounds__(256, 8) void gather_pool_f32(
    const float* __restrict__ emb,
    const int*   __restrict__ x,
    const int*   __restrict__ lengths,
    ushort*      __restrict__ repA)
{
    __shared__ int    xS[LL];
    __shared__ float4 pS[3][75];
    __shared__ float4 pM[3][75];

    const int tid  = threadIdx.x;
    const int lane = tid & 63;
    const int wave = tid >> 6;
    const int row  = blockIdx.x;

    for (int i = tid; i < LL; i += 256) xS[i] = x[row * LL + i];
    const int len = lengths[row];
    __syncthreads();

    const int  t0   = wave * (LL / 4);
    const int  vmax = min(max(len - t0, 0), LL / 4);
    const bool tl   = (lane < 11);
    const float4 z4 = make_float4(0.f, 0.f, 0.f, 0.f);

    float4 s4 = z4, st = z4;
    float4 m4 = make_float4(-INFINITY, -INFINITY, -INFINITY, -INFINITY);
    float4 mt = m4;

    int t = 0;
    #pragma unroll 4
    for (; t < vmax; ++t) {
        const int idx = xS[t0 + t];
        const float4* rp = (const float4*)(emb + (size_t)idx * DIM);
        float4 a = rp[lane];
        float4 b = tl ? rp[64 + lane] : z4;
        s4 = f4add(s4, a); st = f4add(st, b);
        m4 = f4max(m4, a); mt = f4max(mt, b);
    }
    #pragma unroll 4
    for (; t < LL / 4; ++t) {
        const int idx = xS[t0 + t];
        const float4* rp = (const float4*)(emb + (size_t)idx * DIM);
        float4 a = rp[lane];
        float4 b = tl ? rp[64 + lane] : z4;
        s4 = f4add(s4, a); st = f4add(st, b);
    }

    if (wave != 0) {
        pS[wave - 1][lane] = s4; pM[wave - 1][lane] = m4;
        if (tl) { pS[wave - 1][64 + lane] = st; pM[wave - 1][64 + lane] = mt; }
    }
    __syncthreads();
    if (wave == 0) {
        #pragma unroll
        for (int w = 0; w < 3; ++w) {
            s4 = f4add(s4, pS[w][lane]); m4 = f4max(m4, pM[w][lane]);
            if (tl) { st = f4add(st, pS[w][64 + lane]); mt = f4max(mt, pM[w][64 + lane]); }
        }
        const float inv = 1.0f / (float)len;
        const int mtile = row >> 4;
        const int ml    = row & 15;
        ushort* rb = repA + (size_t)mtile * (KT * 512);
        {
            ushort4 q = make_ushort4(f2bf(s4.x*inv), f2bf(s4.y*inv), f2bf(s4.z*inv), f2bf(s4.w*inv));
            *(ushort4*)(rb + a_slot(4 * lane, ml)) = q;
        }
        {
            ushort4 q = make_ushort4(f2bf(m4.x), f2bf(m4.y), f2bf(m4.z), f2bf(m4.w));
            *(ushort4*)(rb + a_slot(300 + 4 * lane, ml)) = q;
        }
        if (tl) {
            ushort4 q1 = make_ushort4(f2bf(st.x*inv), f2bf(st.y*inv), f2bf(st.z*inv), f2bf(st.w*inv));
            *(ushort4*)(rb + a_slot(256 + 4 * lane, ml)) = q1;
            ushort4 q2 = make_ushort4(f2bf(mt.x), f2bf(mt.y), f2bf(mt.z), f2bf(mt.w));
            *(ushort4*)(rb + a_slot(556 + 4 * lane, ml)) = q2;
        }
        if (lane >= 56) rb[a_slot(600 + (lane - 56), ml)] = 0;
    }
}

// ---------------------------------------------------------------------------
// MFMA MLP, n-split x4 (1024 blocks). A-frags staged in LDS; 4 concurrent
// MFMA chains per wave. Layer-2 fused; atomicAdd combine into out (=b2).
// (exact round-0 version)
// ---------------------------------------------------------------------------
__global__ __launch_bounds__(256, 4) void mlp_mfma(
    const ushort* __restrict__ w1p,
    const ushort* __restrict__ repA,
    const float*  __restrict__ b1,
    const float*  __restrict__ W2,
    float*        __restrict__ out)
{
    __shared__ short8 aS[KT * 64];      // 19.5 KB
    __shared__ float  red[4][16][3];

    const int tid  = threadIdx.x;
    const int lane = tid & 63;
    const int wave = tid >> 6;
    const int mt   = blockIdx.x >> 2;
    const int q    = blockIdx.x & 3;

    {
        const short8* ap = (const short8*)(repA + (size_t)mt * (KT * 512));
        for (int i = tid; i < KT * 64; i += 256) aS[i] = ap[i];
    }
    __syncthreads();

    const int nt0 = q * 16 + wave * 4;
    const short8* bp = (const short8*)w1p;

    floatx4 acc[4];
    #pragma unroll
    for (int s = 0; s < 4; ++s) acc[s] = (floatx4){0.f, 0.f, 0.f, 0.f};

    #pragma unroll
    for (int kt = 0; kt < KT; ++kt) {
        const short8 av = aS[kt * 64 + lane];
        const short8 b0 = bp[(kt * NT + nt0 + 0) * 64 + lane];
        const short8 b1v = bp[(kt * NT + nt0 + 1) * 64 + lane];
        const short8 b2v = bp[(kt * NT + nt0 + 2) * 64 + lane];
        const short8 b3 = bp[(kt * NT + nt0 + 3) * 64 + lane];
        acc[0] = __builtin_amdgcn_mfma_f32_16x16x32_bf16(av, b0,  acc[0], 0, 0, 0);
        acc[1] = __builtin_amdgcn_mfma_f32_16x16x32_bf16(av, b1v, acc[1], 0, 0, 0);
        acc[2] = __builtin_amdgcn_mfma_f32_16x16x32_bf16(av, b2v, acc[2], 0, 0, 0);
        acc[3] = __builtin_amdgcn_mfma_f32_16x16x32_bf16(av, b3,  acc[3], 0, 0, 0);
    }

    float po[4][3];
    #pragma unroll
    for (int rg = 0; rg < 4; ++rg)
        #pragma unroll
        for (int j = 0; j < OUTC; ++j) po[rg][j] = 0.f;

    #pragma unroll
    for (int s = 0; s < 4; ++s) {
        const int n = (nt0 + s) * 16 + (lane & 15);
        const bool valid = (n < HIDDEN);
        const float bb  = b1[valid ? n : 0];
        const float w20 = valid ? W2[n * 3 + 0] : 0.f;
        const float w21 = valid ? W2[n * 3 + 1] : 0.f;
        const float w22 = valid ? W2[n * 3 + 2] : 0.f;
        #pragma unroll
        for (int rg = 0; rg < 4; ++rg) {
            const float h = fmaxf(acc[s][rg] + bb, 0.f);
            po[rg][0] = fmaf(h, w20, po[rg][0]);
            po[rg][1] = fmaf(h, w21, po[rg][1]);
            po[rg][2] = fmaf(h, w22, po[rg][2]);
        }
    }

    #pragma unroll
    for (int rg = 0; rg < 4; ++rg) {
        #pragma unroll
        for (int j = 0; j < OUTC; ++j) {
            float v = po[rg][j];
            v += __shfl_xor(v, 1);
            v += __shfl_xor(v, 2);
            v += __shfl_xor(v, 4);
            v += __shfl_xor(v, 8);
            if ((lane & 15) == 0) red[wave][(lane >> 4) * 4 + rg][j] = v;
        }
    }
    __syncthreads();

    if (tid < 16 * OUTC) {
        const int m = tid / OUTC, j = tid % OUTC;
        const float s = red[0][m][j] + red[1][m][j] + red[2][m][j] + red[3][m][j];
        atomicAdd(&out[(size_t)(mt * 16 + m) * OUTC + j], s);
    }
}

extern "C" void kernel_launch(void* const* d_in, const int* in_sizes, int n_in,
                              void* d_out, int out_size, void* d_ws, size_t ws_size,
                              hipStream_t stream) {
    const float* emb = (const float*)d_in[0];
    const float* W1  = (const float*)d_in[1];
    const float* b1  = (const float*)d_in[2];
    const float* W2  = (const float*)d_in[3];
    const float* b2  = (const float*)d_in[4];
    const int*   x   = (const int*)d_in[5];
    const int*   len = (const int*)d_in[6];
    float* out = (float*)d_out;

    // ws layout: [w1p 1.245 MB][repA 4.981 MB][embQ 32.0 MB slab-major]
    const size_t W1P_ELTS  = (size_t)KT * NT * 64 * 8;          // ushorts
    const size_t REPA_ELTS = (size_t)MTILES * KT * 512;         // ushorts
    ushort* w1p  = (ushort*)d_ws;
    ushort* repA = w1p + W1P_ELTS;
    unsigned* embQ = (unsigned*)(repA + REPA_ELTS);
    const size_t need = (W1P_ELTS + REPA_ELTS) * 2 + (size_t)8 * SLABDW * 4;
    const bool doConv = (ws_size >= need);

    const int prepGrid = W1_BLKS + INIT_BLKS + (doConv ? CONV_BLKS : 0);
    hipLaunchKernelGGL(prep_all, dim3(prepGrid), dim3(256), 0, stream,
                       emb, embQ, W1, w1p, b2, out);
    if (doConv) {
        hipLaunchKernelGGL(gather_pool_i8, dim3(BB * 8), dim3(128), 0, stream,
                           embQ, x, len, repA);
    } else {
        hipLaunchKernelGGL(gather_pool_f32, dim3(BB), dim3(256), 0, stream,
                           emb, x, len, repA);
    }
    hipLaunchKernelGGL(mlp_mfma, dim3(MTILES * 4), dim3(256), 0, stream,
                       w1p, repA, b1, W2, out);
}

// Round 6
// 273.460 us; speedup vs baseline: 1.0430x; 1.0430x over previous
//
#include <hip/hip_runtime.h>
#include <math.h>

#define VOCAB  100000
#define DIM    300
#define BB     4096
#define LL     200
#define HIDDEN 1000
#define OUTC   3
#define KT     19          // ceil(600/32) k-tiles of 32
#define NT     64          // n-tiles of 16, padded 1000 -> 1024
#define MTILES (BB / 16)   // 256 m-tiles of 16 rows

#define QSCALE (6.0f / 127.0f)
#define QINV   (127.0f / 6.0f)

#define ROWS_PB 32                                 // vocab rows per conv block
#define W1_BLKS   ((KT * NT * 64 + 255) / 256)     // 304
#define INIT_BLKS ((BB * OUTC + 255) / 256)        // 48
#define CONV_BLKS (VOCAB / ROWS_PB)                // 3125

// embQ layout: 8 slabs x VOCAB rows x 10 dwords (40 B).  Slab s holds dims
// [40s, 40s+40) of every vocab row (slab 7: dims 280-299 + 20 pad bytes).
// Slab = 4.0 MB -> fits one XCD's L2; gather blocks pin slab to XCD via %8.
#define SLABDW (VOCAB * 10)

typedef __attribute__((ext_vector_type(8))) short  short8;
typedef __attribute__((ext_vector_type(4))) float  floatx4;
typedef __attribute__((ext_vector_type(2))) unsigned short ushort2v;

__device__ inline ushort f2bf(float f) {            // RNE float -> bf16 bits
    union { float f; unsigned u; } v; v.f = f;
    unsigned u = v.u;
    u += 0x7fffu + ((u >> 16) & 1u);
    return (ushort)(u >> 16);
}
__device__ inline float4 f4max(float4 a, float4 b) {
    return make_float4(fmaxf(a.x, b.x), fmaxf(a.y, b.y), fmaxf(a.z, b.z), fmaxf(a.w, b.w));
}
__device__ inline float4 f4add(float4 a, float4 b) {
    return make_float4(a.x + b.x, a.y + b.y, a.z + b.z, a.w + b.w);
}
__device__ inline unsigned pkmax16(unsigned a, unsigned b) {  // packed u16 max
    union { unsigned u; ushort2v v; } x, y, r;
    x.u = a; y.u = b;
    r.v = __builtin_elementwise_max(x.v, y.v);
    return r.u;
}

// slot (in ushorts) of element k, row-in-tile ml, in blocked A [kt][64][8]
__device__ inline int a_slot(int k, int ml) {
    const int kt = k >> 5, kk = k & 31;
    return ((kt << 6) + ml + ((kk >> 3) << 4)) * 8 + (kk & 7);
}

__device__ inline unsigned q4(float a, float b, float c, float d) {
    int q0 = min(max(__float2int_rn(a * QINV) + 128, 0), 255);
    int q1 = min(max(__float2int_rn(b * QINV) + 128, 0), 255);
    int q2 = min(max(__float2int_rn(c * QINV) + 128, 0), 255);
    int q3 = min(max(__float2int_rn(d * QINV) + 128, 0), 255);
    return (unsigned)q0 | ((unsigned)q1 << 8) | ((unsigned)q2 << 16) | ((unsigned)q3 << 24);
}

// ---------------------------------------------------------------------------
// prep_all: [0,W1_BLKS) pack W1 -> bf16 B-frag; [..+INIT_BLKS) out=b2;
// [..+CONV_BLKS) quantize emb -> slab-major table (only if doConv).
// Conv blocks stage 32 rows (2400 dwords) in LDS, then write each slab's
// 320-dword region CONTIGUOUSLY (round-5's direct scatter caused 3x write
// amplification: 101 MB written vs 33 MB ideal, prep at 2.5 TB/s).
// ---------------------------------------------------------------------------
__global__ __launch_bounds__(256) void prep_all(
    const float* __restrict__ emb, unsigned* __restrict__ embQ,
    const float* __restrict__ W1,  ushort* __restrict__ w1p,
    const float* __restrict__ b2,  float* __restrict__ out)
{
    __shared__ unsigned ldsQ[ROWS_PB * 75];        // 9.6 KB (conv blocks only)

    const int bid = blockIdx.x;
    const int tid = threadIdx.x;
    if (bid < W1_BLKS) {
        const int g = bid * 256 + tid;                 // (kt*NT + nt)*64 + lane
        if (g >= KT * NT * 64) return;
        const int lane = g & 63;
        const int nt   = (g >> 6) & (NT - 1);
        const int kt   = g >> 12;
        const int n    = nt * 16 + (lane & 15);
        const int kb   = kt * 32 + ((lane >> 4) << 3);
        short8 v;
        #pragma unroll
        for (int j = 0; j < 8; ++j) {
            const int k = kb + j;
            const float f = (k < 600 && n < HIDDEN) ? W1[k * HIDDEN + n] : 0.f;
            v[j] = (short)f2bf(f);
        }
        ((short8*)w1p)[g] = v;
    } else if (bid < W1_BLKS + INIT_BLKS) {
        const int g = (bid - W1_BLKS) * 256 + tid;
        if (g < BB * OUTC) out[g] = b2[g % OUTC];
    } else {
        const int cb = bid - W1_BLKS - INIT_BLKS;      // 0..CONV_BLKS-1
        const int r0 = cb * ROWS_PB;
        // read+quantize: 2400 contiguous float4 -> 2400 LDS dwords
        const float4* rp4 = (const float4*)(emb + (size_t)r0 * DIM);
        #pragma unroll
        for (int k = 0; k < 10; ++k) {
            const int j = 256 * k + tid;               // float4 idx == dword idx
            if (j < ROWS_PB * 75) {
                const float4 f = rp4[j];
                ldsQ[j] = q4(f.x, f.y, f.z, f.w);
            }
        }
        __syncthreads();
        // write: per slab, 320 contiguous dwords (idx = i*10+dw == lane idx)
        #pragma unroll
        for (int sl = 0; sl < 8; ++sl) {
            #pragma unroll
            for (int k = 0; k < 2; ++k) {
                const int idx = 256 * k + tid;         // 0..319
                if (idx < ROWS_PB * 10) {
                    const int i  = idx / 10;
                    const int dw = idx - i * 10;
                    const int d  = 10 * sl + dw;       // dword within padded row
                    const unsigned val = (d < 75) ? ldsQ[i * 75 + d] : 0u;
                    embQ[(size_t)sl * SLABDW + (size_t)r0 * 10 + idx] = val;
                }
            }
        }
    }
}

// ---------------------------------------------------------------------------
// XCD-sliced int8 gather + pool.  Block = (row, slab): blockIdx = row*8 + s,
// so s == blockIdx % 8 pins slab s to XCD s (round-robin dispatch) -> each
// XCD's random gathers stay inside its 4 MB L2-resident slab.
// Each block owns 40 dims of one row outright (full 200-token sum/max).
// 2 waves split tokens (100 each); lane = token-slot(12) x dword-pair(5):
// 8 B loads, SWAR packed-u16 sums (exact, <= 200*255 < 2^16) and maxes.
// Token-slot fold 12->1 in 3 stages (A: +tg+4,+tg+8 with pre-captured
// shfls; B: +tg+2; C: +tg+1) -- each slot counted exactly once.
// ---------------------------------------------------------------------------
__global__ __launch_bounds__(128, 8) void gather_pool_i8(
    const unsigned* __restrict__ embQ,
    const int*      __restrict__ x,
    const int*      __restrict__ lengths,
    ushort*         __restrict__ repA)
{
    __shared__ int      xS[LL];
    __shared__ unsigned pX[5][8];      // wave-1 partials (lanes 0..4)

    const int tid  = threadIdx.x;
    const int lane = tid & 63;
    const int wave = tid >> 6;         // 0,1
    const int row  = blockIdx.x >> 3;
    const int s    = blockIdx.x & 7;   // slab -> XCD

    for (int i = tid; i < LL; i += 128) xS[i] = x[row * LL + i];
    const int len = lengths[row];      // >= 1
    __syncthreads();

    const int  slot = lane % 5;        // dword-pair within 40 B slab row
    const int  tg   = lane / 5;        // token-slot 0..11 (12 on lanes 60-63)
    const bool act  = (lane < 60);

    const int t0   = wave * 100;
    const int vmax = min(max(len - t0, 0), 100);
    const int pm_all = vmax / 12;        // p <  pm_all : all 12 tokens in max
    const int pm_any = (vmax + 11) / 12; // p >= pm_any : sum-only

    const unsigned* sb = embQ + (size_t)s * SLABDW + 2 * slot;

    unsigned sL[2] = {0u, 0u}, sH[2] = {0u, 0u};
    unsigned mL[2] = {0u, 0u}, mH[2] = {0u, 0u};
    // max init 0 safe: codes >= 0 and every row has >= 1 valid token.

    int p = 0;
    for (; p < pm_all; ++p) {          // full-max iterations (t <= 95 < 100)
        const int t   = 12 * p + tg;
        const int idx = xS[t0 + t];
        uint2 v = make_uint2(0u, 0u);
        if (act) v = *(const uint2*)(sb + (size_t)idx * 10);
        const unsigned* ww = (const unsigned*)&v;
        #pragma unroll
        for (int w = 0; w < 2; ++w) {
            const unsigned u  = ww[w];
            const unsigned lo = u & 0x00FF00FFu;
            const unsigned hi = (u >> 8) & 0x00FF00FFu;
            sL[w] += lo;  sH[w] += hi;
            mL[w] = pkmax16(mL[w], lo);
            mH[w] = pkmax16(mH[w], hi);
        }
    }
    for (; p < pm_any; ++p) {          // <=1 mixed iteration (per-lane mask)
        const int  t  = 12 * p + tg;
        const bool on = act && (t < 100);
        const int idx = xS[t0 + (on ? t : 0)];
        uint2 v = make_uint2(0u, 0u);
        if (on) v = *(const uint2*)(sb + (size_t)idx * 10);
        const unsigned mk = (t < vmax) ? 0xFFFFFFFFu : 0u;
        const unsigned* ww = (const unsigned*)&v;
        #pragma unroll
        for (int w = 0; w < 2; ++w) {
            const unsigned u  = ww[w];
            const unsigned lo = u & 0x00FF00FFu;
            const unsigned hi = (u >> 8) & 0x00FF00FFu;
            sL[w] += lo;  sH[w] += hi;
            mL[w] = pkmax16(mL[w], lo & mk);
            mH[w] = pkmax16(mH[w], hi & mk);
        }
    }
    for (; p < 9; ++p) {               // sum-only iterations
        const int  t  = 12 * p + tg;
        const bool on = act && (t < 100);
        const int idx = xS[t0 + (on ? t : 0)];
        uint2 v = make_uint2(0u, 0u);
        if (on) v = *(const uint2*)(sb + (size_t)idx * 10);
        const unsigned* ww = (const unsigned*)&v;
        #pragma unroll
        for (int w = 0; w < 2; ++w) {
            const unsigned u = ww[w];
            sL[w] += u & 0x00FF00FFu;
            sH[w] += (u >> 8) & 0x00FF00FFu;
        }
    }

    // ---- fold token-slots 12 -> 1 (result on tg==0, lanes 0..4) ----
    // Stage A: v[tg] += v[tg+4] + v[tg+8]; capture BOTH shfls before adding.
    {
        const int s1 = slot + 5 * min(tg + 4, 11);
        const int s2 = slot + 5 * min(tg + 8, 11);
        #pragma unroll
        for (int w = 0; w < 2; ++w) {
            const unsigned a1 = (unsigned)__shfl((int)sL[w], s1);
            const unsigned a2 = (unsigned)__shfl((int)sL[w], s2);
            const unsigned b1 = (unsigned)__shfl((int)sH[w], s1);
            const unsigned b2 = (unsigned)__shfl((int)sH[w], s2);
            const unsigned c1v = (unsigned)__shfl((int)mL[w], s1);
            const unsigned c2v = (unsigned)__shfl((int)mL[w], s2);
            const unsigned d1 = (unsigned)__shfl((int)mH[w], s1);
            const unsigned d2 = (unsigned)__shfl((int)mH[w], s2);
            sL[w] += a1 + a2;
            sH[w] += b1 + b2;
            mL[w] = pkmax16(mL[w], pkmax16(c1v, c2v));
            mH[w] = pkmax16(mH[w], pkmax16(d1, d2));
        }
    }
    // Stage B: v[tg] += v[tg+2]
    {
        const int sc = slot + 5 * min(tg + 2, 11);
        #pragma unroll
        for (int w = 0; w < 2; ++w) {
            sL[w] += (unsigned)__shfl((int)sL[w], sc);
            sH[w] += (unsigned)__shfl((int)sH[w], sc);
            mL[w] = pkmax16(mL[w], (unsigned)__shfl((int)mL[w], sc));
            mH[w] = pkmax16(mH[w], (unsigned)__shfl((int)mH[w], sc));
        }
    }
    // Stage C: v[0] += v[1]
    {
        const int sc = slot + 5 * min(tg + 1, 11);
        #pragma unroll
        for (int w = 0; w < 2; ++w) {
            sL[w] += (unsigned)__shfl((int)sL[w], sc);
            sH[w] += (unsigned)__shfl((int)sH[w], sc);
            mL[w] = pkmax16(mL[w], (unsigned)__shfl((int)mL[w], sc));
            mH[w] = pkmax16(mH[w], (unsigned)__shfl((int)mH[w], sc));
        }
    }

    if (wave == 1 && lane < 5) {
        #pragma unroll
        for (int w = 0; w < 2; ++w) {
            pX[lane][w]     = sL[w];
            pX[lane][2 + w] = sH[w];
            pX[lane][4 + w] = mL[w];
            pX[lane][6 + w] = mH[w];
        }
    }
    __syncthreads();
    if (wave == 0 && lane < 5) {
        #pragma unroll
        for (int w = 0; w < 2; ++w) {
            sL[w] += pX[lane][w];
            sH[w] += pX[lane][2 + w];
            mL[w] = pkmax16(mL[w], pX[lane][4 + w]);
            mH[w] = pkmax16(mH[w], pX[lane][6 + w]);
        }

        const float c1 = QSCALE / (float)len;   // mean=(S-128*200)*QSCALE/len
        const int mt = row >> 4;
        const int ml = row & 15;
        ushort* rb = repA + (size_t)mt * (KT * 512);

        #pragma unroll
        for (int w = 0; w < 2; ++w) {
            // dword w of this pair covers dims k0..k0+3
            const int k0 = 40 * s + 8 * slot + 4 * w;
            float S[4], M[4];
            S[0] = (float)(sL[w] & 0xFFFFu);  S[2] = (float)(sL[w] >> 16);
            S[1] = (float)(sH[w] & 0xFFFFu);  S[3] = (float)(sH[w] >> 16);
            M[0] = (float)(mL[w] & 0xFFFFu);  M[2] = (float)(mL[w] >> 16);
            M[1] = (float)(mH[w] & 0xFFFFu);  M[3] = (float)(mH[w] >> 16);
            if (k0 < 300) {                   // real dims (k0 <= 296)
                ushort4 qm = make_ushort4(
                    f2bf((S[0] - 25600.f) * c1), f2bf((S[1] - 25600.f) * c1),
                    f2bf((S[2] - 25600.f) * c1), f2bf((S[3] - 25600.f) * c1));
                *(ushort4*)(rb + a_slot(k0, ml)) = qm;
                ushort4 qx = make_ushort4(
                    f2bf((M[0] - 128.f) * QSCALE), f2bf((M[1] - 128.f) * QSCALE),
                    f2bf((M[2] - 128.f) * QSCALE), f2bf((M[3] - 128.f) * QSCALE));
                *(ushort4*)(rb + a_slot(300 + k0, ml)) = qx;
            } else if (s == 7 && slot == 2 && w == 1) {
                *(ushort4*)(rb + a_slot(600, ml)) = make_ushort4(0, 0, 0, 0);
            } else if (s == 7 && slot == 3 && w == 0) {
                *(ushort4*)(rb + a_slot(604, ml)) = make_ushort4(0, 0, 0, 0);
            }
        }
    }
}

// ---------------------------------------------------------------------------
// fp32 fallback gather (used only if ws too small for embQ).
// ---------------------------------------------------------------------------
__global__ __launch_bounds__(256, 8) void gather_pool_f32(
    const float* __restrict__ emb,
    const int*   __restrict__ x,
    const int*   __restrict__ lengths,
    ushort*      __restrict__ repA)
{
    __shared__ int    xS[LL];
    __shared__ float4 pS[3][75];
    __shared__ float4 pM[3][75];

    const int tid  = threadIdx.x;
    const int lane = tid & 63;
    const int wave = tid >> 6;
    const int row  = blockIdx.x;

    for (int i = tid; i < LL; i += 256) xS[i] = x[row * LL + i];
    const int len = lengths[row];
    __syncthreads();

    const int  t0   = wave * (LL / 4);
    const int  vmax = min(max(len - t0, 0), LL / 4);
    const bool tl   = (lane < 11);
    const float4 z4 = make_float4(0.f, 0.f, 0.f, 0.f);

    float4 s4 = z4, st = z4;
    float4 m4 = make_float4(-INFINITY, -INFINITY, -INFINITY, -INFINITY);
    float4 mt = m4;

    int t = 0;
    #pragma unroll 4
    for (; t < vmax; ++t) {
        const int idx = xS[t0 + t];
        const float4* rp = (const float4*)(emb + (size_t)idx * DIM);
        float4 a = rp[lane];
        float4 b = tl ? rp[64 + lane] : z4;
        s4 = f4add(s4, a); st = f4add(st, b);
        m4 = f4max(m4, a); mt = f4max(mt, b);
    }
    #pragma unroll 4
    for (; t < LL / 4; ++t) {
        const int idx = xS[t0 + t];
        const float4* rp = (const float4*)(emb + (size_t)idx * DIM);
        float4 a = rp[lane];
        float4 b = tl ? rp[64 + lane] : z4;
        s4 = f4add(s4, a); st = f4add(st, b);
    }

    if (wave != 0) {
        pS[wave - 1][lane] = s4; pM[wave - 1][lane] = m4;
        if (tl) { pS[wave - 1][64 + lane] = st; pM[wave - 1][64 + lane] = mt; }
    }
    __syncthreads();
    if (wave == 0) {
        #pragma unroll
        for (int w = 0; w < 3; ++w) {
            s4 = f4add(s4, pS[w][lane]); m4 = f4max(m4, pM[w][lane]);
            if (tl) { st = f4add(st, pS[w][64 + lane]); mt = f4max(mt, pM[w][64 + lane]); }
        }
        const float inv = 1.0f / (float)len;
        const int mtile = row >> 4;
        const int ml    = row & 15;
        ushort* rb = repA + (size_t)mtile * (KT * 512);
        {
            ushort4 q = make_ushort4(f2bf(s4.x*inv), f2bf(s4.y*inv), f2bf(s4.z*inv), f2bf(s4.w*inv));
            *(ushort4*)(rb + a_slot(4 * lane, ml)) = q;
        }
        {
            ushort4 q = make_ushort4(f2bf(m4.x), f2bf(m4.y), f2bf(m4.z), f2bf(m4.w));
            *(ushort4*)(rb + a_slot(300 + 4 * lane, ml)) = q;
        }
        if (tl) {
            ushort4 q1 = make_ushort4(f2bf(st.x*inv), f2bf(st.y*inv), f2bf(st.z*inv), f2bf(st.w*inv));
            *(ushort4*)(rb + a_slot(256 + 4 * lane, ml)) = q1;
            ushort4 q2 = make_ushort4(f2bf(mt.x), f2bf(mt.y), f2bf(mt.z), f2bf(mt.w));
            *(ushort4*)(rb + a_slot(556 + 4 * lane, ml)) = q2;
        }
        if (lane >= 56) rb[a_slot(600 + (lane - 56), ml)] = 0;
    }
}

// ---------------------------------------------------------------------------
// MFMA MLP, n-split x4 (1024 blocks). A-frags staged in LDS; 4 concurrent
// MFMA chains per wave. Layer-2 fused; atomicAdd combine into out (=b2).
// (exact round-0 version)
// ---------------------------------------------------------------------------
__global__ __launch_bounds__(256, 4) void mlp_mfma(
    const ushort* __restrict__ w1p,
    const ushort* __restrict__ repA,
    const float*  __restrict__ b1,
    const float*  __restrict__ W2,
    float*        __restrict__ out)
{
    __shared__ short8 aS[KT * 64];      // 19.5 KB
    __shared__ float  red[4][16][3];

    const int tid  = threadIdx.x;
    const int lane = tid & 63;
    const int wave = tid >> 6;
    const int mt   = blockIdx.x >> 2;
    const int q    = blockIdx.x & 3;

    {
        const short8* ap = (const short8*)(repA + (size_t)mt * (KT * 512));
        for (int i = tid; i < KT * 64; i += 256) aS[i] = ap[i];
    }
    __syncthreads();

    const int nt0 = q * 16 + wave * 4;
    const short8* bp = (const short8*)w1p;

    floatx4 acc[4];
    #pragma unroll
    for (int s = 0; s < 4; ++s) acc[s] = (floatx4){0.f, 0.f, 0.f, 0.f};

    #pragma unroll
    for (int kt = 0; kt < KT; ++kt) {
        const short8 av = aS[kt * 64 + lane];
        const short8 b0 = bp[(kt * NT + nt0 + 0) * 64 + lane];
        const short8 b1v = bp[(kt * NT + nt0 + 1) * 64 + lane];
        const short8 b2v = bp[(kt * NT + nt0 + 2) * 64 + lane];
        const short8 b3 = bp[(kt * NT + nt0 + 3) * 64 + lane];
        acc[0] = __builtin_amdgcn_mfma_f32_16x16x32_bf16(av, b0,  acc[0], 0, 0, 0);
        acc[1] = __builtin_amdgcn_mfma_f32_16x16x32_bf16(av, b1v, acc[1], 0, 0, 0);
        acc[2] = __builtin_amdgcn_mfma_f32_16x16x32_bf16(av, b2v, acc[2], 0, 0, 0);
        acc[3] = __builtin_amdgcn_mfma_f32_16x16x32_bf16(av, b3,  acc[3], 0, 0, 0);
    }

    float po[4][3];
    #pragma unroll
    for (int rg = 0; rg < 4; ++rg)
        #pragma unroll
        for (int j = 0; j < OUTC; ++j) po[rg][j] = 0.f;

    #pragma unroll
    for (int s = 0; s < 4; ++s) {
        const int n = (nt0 + s) * 16 + (lane & 15);
        const bool valid = (n < HIDDEN);
        const float bb  = b1[valid ? n : 0];
        const float w20 = valid ? W2[n * 3 + 0] : 0.f;
        const float w21 = valid ? W2[n * 3 + 1] : 0.f;
        const float w22 = valid ? W2[n * 3 + 2] : 0.f;
        #pragma unroll
        for (int rg = 0; rg < 4; ++rg) {
            const float h = fmaxf(acc[s][rg] + bb, 0.f);
            po[rg][0] = fmaf(h, w20, po[rg][0]);
            po[rg][1] = fmaf(h, w21, po[rg][1]);
            po[rg][2] = fmaf(h, w22, po[rg][2]);
        }
    }

    #pragma unroll
    for (int rg = 0; rg < 4; ++rg) {
        #pragma unroll
        for (int j = 0; j < OUTC; ++j) {
            float v = po[rg][j];
            v += __shfl_xor(v, 1);
            v += __shfl_xor(v, 2);
            v += __shfl_xor(v, 4);
            v += __shfl_xor(v, 8);
            if ((lane & 15) == 0) red[wave][(lane >> 4) * 4 + rg][j] = v;
        }
    }
    __syncthreads();

    if (tid < 16 * OUTC) {
        const int m = tid / OUTC, j = tid % OUTC;
        const float s = red[0][m][j] + red[1][m][j] + red[2][m][j] + red[3][m][j];
        atomicAdd(&out[(size_t)(mt * 16 + m) * OUTC + j], s);
    }
}

extern "C" void kernel_launch(void* const* d_in, const int* in_sizes, int n_in,
                              void* d_out, int out_size, void* d_ws, size_t ws_size,
                              hipStream_t stream) {
    const float* emb = (const float*)d_in[0];
    const float* W1  = (const float*)d_in[1];
    const float* b1  = (const float*)d_in[2];
    const float* W2  = (const float*)d_in[3];
    const float* b2  = (const float*)d_in[4];
    const int*   x   = (const int*)d_in[5];
    const int*   len = (const int*)d_in[6];
    float* out = (float*)d_out;

    // ws layout: [w1p 1.245 MB][repA 4.981 MB][embQ 32.0 MB slab-major]
    const size_t W1P_ELTS  = (size_t)KT * NT * 64 * 8;          // ushorts
    const size_t REPA_ELTS = (size_t)MTILES * KT * 512;         // ushorts
    ushort* w1p  = (ushort*)d_ws;
    ushort* repA = w1p + W1P_ELTS;
    unsigned* embQ = (unsigned*)(repA + REPA_ELTS);
    const size_t need = (W1P_ELTS + REPA_ELTS) * 2 + (size_t)8 * SLABDW * 4;
    const bool doConv = (ws_size >= need);

    const int prepGrid = W1_BLKS + INIT_BLKS + (doConv ? CONV_BLKS : 0);
    hipLaunchKernelGGL(prep_all, dim3(prepGrid), dim3(256), 0, stream,
                       emb, embQ, W1, w1p, b2, out);
    if (doConv) {
        hipLaunchKernelGGL(gather_pool_i8, dim3(BB * 8), dim3(128), 0, stream,
                           embQ, x, len, repA);
    } else {
        hipLaunchKernelGGL(gather_pool_f32, dim3(BB), dim3(256), 0, stream,
                           emb, x, len, repA);
    }
    hipLaunchKernelGGL(mlp_mfma, dim3(MTILES * 4), dim3(256), 0, stream,
                       w1p, repA, b1, W2, out);
}

// Round 7
// 256.422 us; speedup vs baseline: 1.1123x; 1.0664x over previous
//
#include <hip/hip_runtime.h>
#include <math.h>

#define VOCAB  100000
#define DIM    300
#define IDIM   320         // padded int8 row: 320 B
#define BB     4096
#define LL     200
#define HIDDEN 1000
#define OUTC   3
#define KT     19          // ceil(600/32) k-tiles of 32
#define NT     64          // n-tiles of 16, padded 1000 -> 1024
#define MTILES (BB / 16)   // 256 m-tiles of 16 rows

#define QSCALE (6.0f / 127.0f)
#define QINV   (127.0f / 6.0f)

#define W1_BLKS   ((KT * NT * 64 + 255) / 256)     // 304
#define INIT_BLKS ((BB * OUTC + 255) / 256)        // 48
#define CONV_BLKS ((VOCAB * 20 + 255) / 256)       // 7813

typedef __attribute__((ext_vector_type(8))) short  short8;
typedef __attribute__((ext_vector_type(4))) float  floatx4;
typedef __attribute__((ext_vector_type(2))) unsigned short ushort2v;

__device__ inline ushort f2bf(float f) {            // RNE float -> bf16 bits
    union { float f; unsigned u; } v; v.f = f;
    unsigned u = v.u;
    u += 0x7fffu + ((u >> 16) & 1u);
    return (ushort)(u >> 16);
}
__device__ inline float4 f4max(float4 a, float4 b) {
    return make_float4(fmaxf(a.x, b.x), fmaxf(a.y, b.y), fmaxf(a.z, b.z), fmaxf(a.w, b.w));
}
__device__ inline float4 f4add(float4 a, float4 b) {
    return make_float4(a.x + b.x, a.y + b.y, a.z + b.z, a.w + b.w);
}
__device__ inline unsigned pkmax16(unsigned a, unsigned b) {  // packed u16 max
    union { unsigned u; ushort2v v; } x, y, r;
    x.u = a; y.u = b;
    r.v = __builtin_elementwise_max(x.v, y.v);
    return r.u;
}

// slot (in ushorts) of element k, row-in-tile ml, in blocked A [kt][64][8]
__device__ inline int a_slot(int k, int ml) {
    const int kt = k >> 5, kk = k & 31;
    return ((kt << 6) + ml + ((kk >> 3) << 4)) * 8 + (kk & 7);
}

__device__ inline unsigned q4(float a, float b, float c, float d) {
    int q0 = min(max(__float2int_rn(a * QINV) + 128, 0), 255);
    int q1 = min(max(__float2int_rn(b * QINV) + 128, 0), 255);
    int q2 = min(max(__float2int_rn(c * QINV) + 128, 0), 255);
    int q3 = min(max(__float2int_rn(d * QINV) + 128, 0), 255);
    return (unsigned)q0 | ((unsigned)q1 << 8) | ((unsigned)q2 << 16) | ((unsigned)q3 << 24);
}

// ---------------------------------------------------------------------------
// prep_all: [0,W1_BLKS) pack W1 -> bf16 B-frag; [..+INIT_BLKS) out=b2;
// [..+CONV_BLKS) quantize emb -> uint8[100000][320]  (only if doConv).
// ---------------------------------------------------------------------------
__global__ __launch_bounds__(256) void prep_all(
    const float* __restrict__ emb, unsigned char* __restrict__ embQ,
    const float* __restrict__ W1,  ushort* __restrict__ w1p,
    const float* __restrict__ b2,  float* __restrict__ out)
{
    const int bid = blockIdx.x;
    const int tid = threadIdx.x;
    if (bid < W1_BLKS) {
        const int g = bid * 256 + tid;                 // (kt*NT + nt)*64 + lane
        if (g >= KT * NT * 64) return;
        const int lane = g & 63;
        const int nt   = (g >> 6) & (NT - 1);
        const int kt   = g >> 12;
        const int n    = nt * 16 + (lane & 15);
        const int kb   = kt * 32 + ((lane >> 4) << 3);
        short8 v;
        #pragma unroll
        for (int j = 0; j < 8; ++j) {
            const int k = kb + j;
            const float f = (k < 600 && n < HIDDEN) ? W1[k * HIDDEN + n] : 0.f;
            v[j] = (short)f2bf(f);
        }
        ((short8*)w1p)[g] = v;
    } else if (bid < W1_BLKS + INIT_BLKS) {
        const int g = (bid - W1_BLKS) * 256 + tid;
        if (g < BB * OUTC) out[g] = b2[g % OUTC];
    } else {
        const int g = (bid - W1_BLKS - INIT_BLKS) * 256 + tid;   // row*20 + c
        if (g >= VOCAB * 20) return;
        const int row = g / 20;
        const int c   = g - row * 20;
        const float4* rp = (const float4*)(emb + (size_t)row * DIM);
        uint4 o;
        unsigned* ow = (unsigned*)&o;
        #pragma unroll
        for (int v = 0; v < 4; ++v) {
            const int fi = 4 * c + v;
            float4 f = (fi < 75) ? rp[fi] : make_float4(0.f, 0.f, 0.f, 0.f);
            ow[v] = q4(f.x, f.y, f.z, f.w);
        }
        *(uint4*)(embQ + (size_t)g * 16) = o;
    }
}

// ---------------------------------------------------------------------------
// int8 gather + pool with SWAR accumulate. 1 row/block, 4 waves = token
// quarters (25 token-pairs each). Lanes 0..19 token A, 20..39 token B; lane
// group-index lg covers dims 16lg..16lg+15. Sums as packed 2x16-bit raw
// codes (exact: <= 200*255 < 2^16); max as packed-u16 of codes.
// ---------------------------------------------------------------------------
__global__ __launch_bounds__(256, 8) void gather_pool_i8(
    const unsigned char* __restrict__ embQ,
    const int*           __restrict__ x,
    const int*           __restrict__ lengths,
    ushort*              __restrict__ repA)
{
    __shared__ int      xS[LL];
    __shared__ unsigned pS[3][20][8];    // packed sums   (sLo0..3, sHi0..3)
    __shared__ unsigned pM[3][20][8];    // packed maxes

    const int tid  = threadIdx.x;
    const int lane = tid & 63;
    const int wave = tid >> 6;
    const int row  = blockIdx.x;

    for (int i = tid; i < LL; i += 256) xS[i] = x[row * LL + i];
    const int len = lengths[row];                 // >= 1
    __syncthreads();

    const int  t0   = wave * 50;
    const int  vmax = min(max(len - t0, 0), 50);
    const bool ga   = (lane < 20);
    const bool ld   = (lane < 40);
    const int  lg   = ga ? lane : (lane - 20);

    unsigned sLo[4], sHi[4], mLo[4], mHi[4];
    #pragma unroll
    for (int w = 0; w < 4; ++w) { sLo[w] = sHi[w] = 0u; mLo[w] = mHi[w] = 0u; }
    // max init 0 is safe: codes >= 0, and every row has >= 1 valid token.

    uint4 raw = make_uint4(0, 0, 0, 0);
    const int full = vmax >> 1;
    int p = 0;
    for (; p < full; ++p) {                       // both tokens in max region
        const int tA  = t0 + 2 * p;
        const int idx = ga ? xS[tA] : xS[tA + 1];
        if (ld) raw = *(const uint4*)(embQ + (size_t)idx * IDIM + 16 * lg);
        const unsigned* ww = (const unsigned*)&raw;
        #pragma unroll
        for (int w = 0; w < 4; ++w) {
            const unsigned u  = ww[w];
            const unsigned lo = u & 0x00FF00FFu;
            const unsigned hi = (u >> 8) & 0x00FF00FFu;
            sLo[w] += lo;  sHi[w] += hi;
            mLo[w] = pkmax16(mLo[w], lo);
            mHi[w] = pkmax16(mHi[w], hi);
        }
    }
    if (vmax & 1) {                               // A in max region, B sum-only
        const int tA  = t0 + 2 * p;
        const int idx = ga ? xS[tA] : xS[tA + 1];
        if (ld) raw = *(const uint4*)(embQ + (size_t)idx * IDIM + 16 * lg);
        const unsigned* ww = (const unsigned*)&raw;
        #pragma unroll
        for (int w = 0; w < 4; ++w) {
            const unsigned u  = ww[w];
            const unsigned lo = u & 0x00FF00FFu;
            const unsigned hi = (u >> 8) & 0x00FF00FFu;
            sLo[w] += lo;  sHi[w] += hi;
            if (ga) {
                mLo[w] = pkmax16(mLo[w], lo);
                mHi[w] = pkmax16(mHi[w], hi);
            }
        }
        ++p;
    }
    for (; p < 25; ++p) {                         // sum-only pairs
        const int tA  = t0 + 2 * p;
        const int idx = ga ? xS[tA] : xS[tA + 1];
        if (ld) raw = *(const uint4*)(embQ + (size_t)idx * IDIM + 16 * lg);
        const unsigned* ww = (const unsigned*)&raw;
        #pragma unroll
        for (int w = 0; w < 4; ++w) {
            const unsigned u = ww[w];
            sLo[w] += u & 0x00FF00FFu;
            sHi[w] += (u >> 8) & 0x00FF00FFu;
        }
    }

    // combine token-A / token-B lane groups
    {
        const int src = ga ? (lane + 20) : lane;
        #pragma unroll
        for (int w = 0; w < 4; ++w) {
            sLo[w] += (unsigned)__shfl((int)sLo[w], src);
            sHi[w] += (unsigned)__shfl((int)sHi[w], src);
            mLo[w] = pkmax16(mLo[w], (unsigned)__shfl((int)mLo[w], src));
            mHi[w] = pkmax16(mHi[w], (unsigned)__shfl((int)mHi[w], src));
        }
    }

    if (wave != 0 && ga) {
        #pragma unroll
        for (int w = 0; w < 4; ++w) {
            pS[wave - 1][lane][w]     = sLo[w];
            pS[wave - 1][lane][4 + w] = sHi[w];
            pM[wave - 1][lane][w]     = mLo[w];
            pM[wave - 1][lane][4 + w] = mHi[w];
        }
    }
    __syncthreads();
    if (wave == 0 && ga) {
        #pragma unroll
        for (int wv = 0; wv < 3; ++wv)
            #pragma unroll
            for (int w = 0; w < 4; ++w) {
                sLo[w] += pS[wv][lane][w];
                sHi[w] += pS[wv][lane][4 + w];
                mLo[w] = pkmax16(mLo[w], pM[wv][lane][w]);
                mHi[w] = pkmax16(mHi[w], pM[wv][lane][4 + w]);
            }

        // unpack to per-dim floats: word w holds dims {4w,4w+1,4w+2,4w+3}
        float s[16], m[16];
        #pragma unroll
        for (int w = 0; w < 4; ++w) {
            s[4*w+0] = (float)(sLo[w] & 0xFFFFu);
            s[4*w+2] = (float)(sLo[w] >> 16);
            s[4*w+1] = (float)(sHi[w] & 0xFFFFu);
            s[4*w+3] = (float)(sHi[w] >> 16);
            m[4*w+0] = (float)(mLo[w] & 0xFFFFu);
            m[4*w+2] = (float)(mLo[w] >> 16);
            m[4*w+1] = (float)(mHi[w] & 0xFFFFu);
            m[4*w+3] = (float)(mHi[w] >> 16);
        }

        const float c1 = QSCALE / (float)len;     // mean=(S-128*200)*QSCALE/len
        const int mt = row >> 4;
        const int ml = row & 15;
        ushort* rb = repA + (size_t)mt * (KT * 512);

        ushort mv[16];
        #pragma unroll
        for (int j = 0; j < 16; ++j) mv[j] = f2bf((m[j] - 128.f) * QSCALE);

        if (lane < 18) {
            #pragma unroll
            for (int h = 0; h < 2; ++h) {
                short8 q;
                #pragma unroll
                for (int j = 0; j < 8; ++j)
                    q[j] = (short)f2bf((s[8*h + j] - 25600.f) * c1);
                *(short8*)(rb + a_slot(16 * lane + 8 * h, ml)) = q;
            }
            #pragma unroll
            for (int h = 0; h < 2; ++h) {
                const int k0 = 300 + 16 * lane + 8 * h;
                *(ushort4*)(rb + a_slot(k0, ml)) =
                    make_ushort4(mv[8*h+0], mv[8*h+1], mv[8*h+2], mv[8*h+3]);
                *(ushort4*)(rb + a_slot(k0 + 4, ml)) =
                    make_ushort4(mv[8*h+4], mv[8*h+5], mv[8*h+6], mv[8*h+7]);
            }
        } else if (lane == 18) {
            short8 q;
            #pragma unroll
            for (int j = 0; j < 8; ++j) q[j] = (short)f2bf((s[j] - 25600.f) * c1);
            *(short8*)(rb + a_slot(288, ml)) = q;
            *(ushort4*)(rb + a_slot(296, ml)) =
                make_ushort4(f2bf((s[8] - 25600.f) * c1), f2bf((s[9] - 25600.f) * c1),
                             f2bf((s[10] - 25600.f) * c1), f2bf((s[11] - 25600.f) * c1));
            *(ushort4*)(rb + a_slot(588, ml)) = make_ushort4(mv[0], mv[1], mv[2], mv[3]);
            *(ushort4*)(rb + a_slot(592, ml)) = make_ushort4(mv[4], mv[5], mv[6], mv[7]);
            *(ushort4*)(rb + a_slot(596, ml)) = make_ushort4(mv[8], mv[9], mv[10], mv[11]);
            *(ushort4*)(rb + a_slot(600, ml)) = make_ushort4(0, 0, 0, 0);
        } else {
            *(ushort4*)(rb + a_slot(604, ml)) = make_ushort4(0, 0, 0, 0);
        }
    }
}

// ---------------------------------------------------------------------------
// fp32 fallback gather (used only if ws too small for embQ).
// ---------------------------------------------------------------------------
__global__ __launch_bounds__(256, 8) void gather_pool_f32(
    const float* __restrict__ emb,
    const int*   __restrict__ x,
    const int*   __restrict__ lengths,
    ushort*      __restrict__ repA)
{
    __shared__ int    xS[LL];
    __shared__ float4 pS[3][75];
    __shared__ float4 pM[3][75];

    const int tid  = threadIdx.x;
    const int lane = tid & 63;
    const int wave = tid >> 6;
    const int row  = blockIdx.x;

    for (int i = tid; i < LL; i += 256) xS[i] = x[row * LL + i];
    const int len = lengths[row];
    __syncthreads();

    const int  t0   = wave * (LL / 4);
    const int  vmax = min(max(len - t0, 0), LL / 4);
    const bool tl   = (lane < 11);
    const float4 z4 = make_float4(0.f, 0.f, 0.f, 0.f);

    float4 s4 = z4, st = z4;
    float4 m4 = make_float4(-INFINITY, -INFINITY, -INFINITY, -INFINITY);
    float4 mt = m4;

    int t = 0;
    #pragma unroll 4
    for (; t < vmax; ++t) {
        const int idx = xS[t0 + t];
        const float4* rp = (const float4*)(emb + (size_t)idx * DIM);
        float4 a = rp[lane];
        float4 b = tl ? rp[64 + lane] : z4;
        s4 = f4add(s4, a); st = f4add(st, b);
        m4 = f4max(m4, a); mt = f4max(mt, b);
    }
    #pragma unroll 4
    for (; t < LL / 4; ++t) {
        const int idx = xS[t0 + t];
        const float4* rp = (const float4*)(emb + (size_t)idx * DIM);
        float4 a = rp[lane];
        float4 b = tl ? rp[64 + lane] : z4;
        s4 = f4add(s4, a); st = f4add(st, b);
    }

    if (wave != 0) {
        pS[wave - 1][lane] = s4; pM[wave - 1][lane] = m4;
        if (tl) { pS[wave - 1][64 + lane] = st; pM[wave - 1][64 + lane] = mt; }
    }
    __syncthreads();
    if (wave == 0) {
        #pragma unroll
        for (int w = 0; w < 3; ++w) {
            s4 = f4add(s4, pS[w][lane]); m4 = f4max(m4, pM[w][lane]);
            if (tl) { st = f4add(st, pS[w][64 + lane]); mt = f4max(mt, pM[w][64 + lane]); }
        }
        const float inv = 1.0f / (float)len;
        const int mtile = row >> 4;
        const int ml    = row & 15;
        ushort* rb = repA + (size_t)mtile * (KT * 512);
        {
            ushort4 q = make_ushort4(f2bf(s4.x*inv), f2bf(s4.y*inv), f2bf(s4.z*inv), f2bf(s4.w*inv));
            *(ushort4*)(rb + a_slot(4 * lane, ml)) = q;
        }
        {
            ushort4 q = make_ushort4(f2bf(m4.x), f2bf(m4.y), f2bf(m4.z), f2bf(m4.w));
            *(ushort4*)(rb + a_slot(300 + 4 * lane, ml)) = q;
        }
        if (tl) {
            ushort4 q1 = make_ushort4(f2bf(st.x*inv), f2bf(st.y*inv), f2bf(st.z*inv), f2bf(st.w*inv));
            *(ushort4*)(rb + a_slot(256 + 4 * lane, ml)) = q1;
            ushort4 q2 = make_ushort4(f2bf(mt.x), f2bf(mt.y), f2bf(mt.z), f2bf(mt.w));
            *(ushort4*)(rb + a_slot(556 + 4 * lane, ml)) = q2;
        }
        if (lane >= 56) rb[a_slot(600 + (lane - 56), ml)] = 0;
    }
}

// ---------------------------------------------------------------------------
// MFMA MLP, n-split x4 (1024 blocks). A-frags staged in LDS; 4 concurrent
// MFMA chains per wave. Layer-2 fused; atomicAdd combine into out (=b2).
// ---------------------------------------------------------------------------
__global__ __launch_bounds__(256, 4) void mlp_mfma(
    const ushort* __restrict__ w1p,
    const ushort* __restrict__ repA,
    const float*  __restrict__ b1,
    const float*  __restrict__ W2,
    float*        __restrict__ out)
{
    __shared__ short8 aS[KT * 64];      // 19.5 KB
    __shared__ float  red[4][16][3];

    const int tid  = threadIdx.x;
    const int lane = tid & 63;
    const int wave = tid >> 6;
    const int mt   = blockIdx.x >> 2;
    const int q    = blockIdx.x & 3;

    {
        const short8* ap = (const short8*)(repA + (size_t)mt * (KT * 512));
        for (int i = tid; i < KT * 64; i += 256) aS[i] = ap[i];
    }
    __syncthreads();

    const int nt0 = q * 16 + wave * 4;
    const short8* bp = (const short8*)w1p;

    floatx4 acc[4];
    #pragma unroll
    for (int s = 0; s < 4; ++s) acc[s] = (floatx4){0.f, 0.f, 0.f, 0.f};

    #pragma unroll
    for (int kt = 0; kt < KT; ++kt) {
        const short8 av = aS[kt * 64 + lane];
        const short8 b0 = bp[(kt * NT + nt0 + 0) * 64 + lane];
        const short8 b1v = bp[(kt * NT + nt0 + 1) * 64 + lane];
        const short8 b2v = bp[(kt * NT + nt0 + 2) * 64 + lane];
        const short8 b3 = bp[(kt * NT + nt0 + 3) * 64 + lane];
        acc[0] = __builtin_amdgcn_mfma_f32_16x16x32_bf16(av, b0,  acc[0], 0, 0, 0);
        acc[1] = __builtin_amdgcn_mfma_f32_16x16x32_bf16(av, b1v, acc[1], 0, 0, 0);
        acc[2] = __builtin_amdgcn_mfma_f32_16x16x32_bf16(av, b2v, acc[2], 0, 0, 0);
        acc[3] = __builtin_amdgcn_mfma_f32_16x16x32_bf16(av, b3,  acc[3], 0, 0, 0);
    }

    float po[4][3];
    #pragma unroll
    for (int rg = 0; rg < 4; ++rg)
        #pragma unroll
        for (int j = 0; j < OUTC; ++j) po[rg][j] = 0.f;

    #pragma unroll
    for (int s = 0; s < 4; ++s) {
        const int n = (nt0 + s) * 16 + (lane & 15);
        const bool valid = (n < HIDDEN);
        const float bb  = b1[valid ? n : 0];
        const float w20 = valid ? W2[n * 3 + 0] : 0.f;
        const float w21 = valid ? W2[n * 3 + 1] : 0.f;
        const float w22 = valid ? W2[n * 3 + 2] : 0.f;
        #pragma unroll
        for (int rg = 0; rg < 4; ++rg) {
            const float h = fmaxf(acc[s][rg] + bb, 0.f);
            po[rg][0] = fmaf(h, w20, po[rg][0]);
            po[rg][1] = fmaf(h, w21, po[rg][1]);
            po[rg][2] = fmaf(h, w22, po[rg][2]);
        }
    }

    #pragma unroll
    for (int rg = 0; rg < 4; ++rg) {
        #pragma unroll
        for (int j = 0; j < OUTC; ++j) {
            float v = po[rg][j];
            v += __shfl_xor(v, 1);
            v += __shfl_xor(v, 2);
            v += __shfl_xor(v, 4);
            v += __shfl_xor(v, 8);
            if ((lane & 15) == 0) red[wave][(lane >> 4) * 4 + rg][j] = v;
        }
    }
    __syncthreads();

    if (tid < 16 * OUTC) {
        const int m = tid / OUTC, j = tid % OUTC;
        const float s = red[0][m][j] + red[1][m][j] + red[2][m][j] + red[3][m][j];
        atomicAdd(&out[(size_t)(mt * 16 + m) * OUTC + j], s);
    }
}

extern "C" void kernel_launch(void* const* d_in, const int* in_sizes, int n_in,
                              void* d_out, int out_size, void* d_ws, size_t ws_size,
                              hipStream_t stream) {
    const float* emb = (const float*)d_in[0];
    const float* W1  = (const float*)d_in[1];
    const float* b1  = (const float*)d_in[2];
    const float* W2  = (const float*)d_in[3];
    const float* b2  = (const float*)d_in[4];
    const int*   x   = (const int*)d_in[5];
    const int*   len = (const int*)d_in[6];
    float* out = (float*)d_out;

    // ws layout: [w1p 1.245 MB][repA 4.981 MB][embQ 32.0 MB]
    const size_t W1P_ELTS  = (size_t)KT * NT * 64 * 8;          // ushorts
    const size_t REPA_ELTS = (size_t)MTILES * KT * 512;         // ushorts
    ushort* w1p  = (ushort*)d_ws;
    ushort* repA = w1p + W1P_ELTS;
    unsigned char* embQ = (unsigned char*)(repA + REPA_ELTS);
    const size_t need = (W1P_ELTS + REPA_ELTS) * 2 + (size_t)VOCAB * IDIM;
    const bool doConv = (ws_size >= need);

    const int prepGrid = W1_BLKS + INIT_BLKS + (doConv ? CONV_BLKS : 0);
    hipLaunchKernelGGL(prep_all, dim3(prepGrid), dim3(256), 0, stream,
                       emb, embQ, W1, w1p, b2, out);
    if (doConv) {
        hipLaunchKernelGGL(gather_pool_i8, dim3(BB), dim3(256), 0, stream,
                           embQ, x, len, repA);
    } else {
        hipLaunchKernelGGL(gather_pool_f32, dim3(BB), dim3(256), 0, stream,
                           emb, x, len, repA);
    }
    hipLaunchKernelGGL(mlp_mfma, dim3(MTILES * 4), dim3(256), 0, stream,
                       w1p, repA, b1, W2, out);
}